// Round 3
// baseline (515.518 us; speedup 1.0000x reference)
//
#include <hip/hip_runtime.h>
#include <cstdint>
#include <cstddef>

#define BETA 5.5f
#define ALPHA 0.5f

constexpr int D   = 512;     // feature dim
constexpr int NB  = 4096;    // queries
constexpr int NK  = 16384;   // keys
constexpr int BQ  = 64;      // query tile per block
constexpr int BN  = 64;      // key chunk
constexpr int NSPLIT = 8;    // one nsplit per XCD (blockIdx&7 ~ XCD id) -> 4MB L2 working set
constexpr int NRANGE = NK / NSPLIT;   // 2048
constexpr int CHUNKS = NRANGE / BN;   // 32
constexpr int KROW = D + 8;           // padded LDS row (bf16 elems)
constexpr int PROW = BN + 8;          // padded P row: 72

typedef __attribute__((ext_vector_type(8))) short    short8;
typedef __attribute__((ext_vector_type(4))) float    floatx4;
typedef __attribute__((ext_vector_type(4))) uint32_t uint4v;
typedef __attribute__((ext_vector_type(2))) uint32_t uint2v;

__device__ inline uint32_t f2bf1(float f) {
  union { float f; uint32_t u; } v; v.f = f;
  return (v.u + 0x7FFFu + ((v.u >> 16) & 1u)) >> 16;   // RNE
}
__device__ inline uint32_t pack2(float a, float b) {
  return f2bf1(a) | (f2bf1(b) << 16);
}

__device__ inline void load_lds16(const void* g, void* l) {
  __builtin_amdgcn_global_load_lds(
      (const __attribute__((address_space(1))) uint32_t*)g,
      (__attribute__((address_space(3))) uint32_t*)l, 16, 0, 0);
}

// ---------------- normalize Q -> Qn (bf16), and init out = Q ----------------
__global__ void norm_q_kernel(const float* __restrict__ q,
                              float* __restrict__ out,
                              unsigned short* __restrict__ Qn) {
  const int wave = threadIdx.x >> 6, lane = threadIdx.x & 63;
  const int row = blockIdx.x * 4 + wave;
  const float4* qr = (const float4*)(q + (size_t)row * D);
  float4 a = qr[lane * 2];
  float4 b = qr[lane * 2 + 1];
  float ss = a.x*a.x + a.y*a.y + a.z*a.z + a.w*a.w
           + b.x*b.x + b.y*b.y + b.z*b.z + b.w*b.w;
#pragma unroll
  for (int m = 32; m >= 1; m >>= 1) ss += __shfl_xor(ss, m, 64);
  const float sc = 1.0f / fmaxf(sqrtf(ss), 1e-12f);
  float4* orow = (float4*)(out + (size_t)row * D);
  orow[lane * 2]     = a;
  orow[lane * 2 + 1] = b;
  uint4v w;
  w.x = pack2(a.x*sc, a.y*sc); w.y = pack2(a.z*sc, a.w*sc);
  w.z = pack2(b.x*sc, b.y*sc); w.w = pack2(b.z*sc, b.w*sc);
  *(uint4v*)(Qn + (size_t)row * D + lane * 8) = w;
}

// ------------- normalize K -> Kn (bf16) and KnT (bf16, transposed) ----------
__global__ void norm_k_kernel(const float* __restrict__ k,
                              unsigned short* __restrict__ Kn,
                              unsigned short* __restrict__ KnT) {
  __shared__ unsigned short tile[64 * KROW];
  const int wave = threadIdx.x >> 6, lane = threadIdx.x & 63;
  const int n0 = blockIdx.x * 64;
#pragma unroll 1
  for (int i = 0; i < 16; ++i) {
    const int rl = wave * 16 + i;
    const int n  = n0 + rl;
    const float4* kr = (const float4*)(k + (size_t)n * D);
    float4 a = kr[lane * 2], b = kr[lane * 2 + 1];
    float ss = a.x*a.x + a.y*a.y + a.z*a.z + a.w*a.w
             + b.x*b.x + b.y*b.y + b.z*b.z + b.w*b.w;
#pragma unroll
    for (int m = 32; m >= 1; m >>= 1) ss += __shfl_xor(ss, m, 64);
    const float sc = 1.0f / fmaxf(sqrtf(ss), 1e-12f);
    uint4v w;
    w.x = pack2(a.x*sc, a.y*sc); w.y = pack2(a.z*sc, a.w*sc);
    w.z = pack2(b.x*sc, b.y*sc); w.w = pack2(b.z*sc, b.w*sc);
    *(uint4v*)(Kn + (size_t)n * D + lane * 8) = w;
    *(uint4v*)&tile[rl * KROW + lane * 8]     = w;
  }
  __syncthreads();
  const int dsub = threadIdx.x >> 3;        // 0..31
  const int nl   = (threadIdx.x & 7) * 8;   // 0..56
#pragma unroll 1
  for (int iter = 0; iter < 16; ++iter) {
    const int d = iter * 32 + dsub;
    uint4v w;
    w.x = (uint32_t)tile[(nl+0)*KROW + d] | ((uint32_t)tile[(nl+1)*KROW + d] << 16);
    w.y = (uint32_t)tile[(nl+2)*KROW + d] | ((uint32_t)tile[(nl+3)*KROW + d] << 16);
    w.z = (uint32_t)tile[(nl+4)*KROW + d] | ((uint32_t)tile[(nl+5)*KROW + d] << 16);
    w.w = (uint32_t)tile[(nl+6)*KROW + d] | ((uint32_t)tile[(nl+7)*KROW + d] << 16);
    *(uint4v*)(KnT + (size_t)d * NK + n0 + nl) = w;
  }
}

// ---------------- fused: S = Qn Kn^T chunk, P = exp, O += P Kn --------------
// Pipelined (K_lds/P_lds/ktf double-buffered, ONE barrier per chunk).
// NSPLIT=8 keeps each XCD's K working set (Kn+KnT slice = 4MB) L2-resident,
// so block drift cannot cause L2 thrash (the round-2 failure mode).
__global__ __launch_bounds__(512, 2) void fused_kernel(
    const unsigned short* __restrict__ Qn,
    const unsigned short* __restrict__ Kn,
    const unsigned short* __restrict__ KnT,
    float* __restrict__ out) {
  __shared__ unsigned short K_lds[2][BN * KROW];   // 2 x 66.5 KB
  __shared__ unsigned short P_lds[2][BQ * PROW];   // 2 x 9.2 KB   (total 148 KB)

  const int tid  = threadIdx.x;
  const int wave = tid >> 6, lane = tid & 63;
  const int l15  = lane & 15, quad = lane >> 4;
  const int nsplit = blockIdx.x & (NSPLIT - 1); // one nsplit per XCD (round-robin)
  const int qtile  = blockIdx.x >> 3;           // 0..63, across 2 dispatch passes
  const int q0     = qtile * BQ;
  const int nbase  = nsplit * NRANGE;
  const int tb = wave & 3, nh = wave >> 2;

  // Q B-fragments in registers: wave's 16-col b-tile, all 512 d (64 VGPR)
  short8 qf[16];
  {
    const unsigned short* qrow = Qn + (size_t)(q0 + tb * 16 + l15) * D + quad * 8;
#pragma unroll
    for (int kb = 0; kb < 16; ++kb) qf[kb] = *(const short8*)(qrow + kb * 32);
  }

  floatx4 oacc[4][4] = {};   // wave's 64x64 O slice (cols wave*64..+63)
  short8 ktf[2][2][4];       // double-buffered KnT B-fragments

  // prologue: stage chunk 0 into buf0, prefetch its KnT frags
#pragma unroll
  for (int i = 0; i < 8; ++i) {
    const int row = wave * 8 + i;
    load_lds16(Kn + (size_t)(nbase + row) * D + lane * 8, &K_lds[0][row * KROW]);
  }
#pragma unroll
  for (int kb2 = 0; kb2 < 2; ++kb2)
#pragma unroll
    for (int td = 0; td < 4; ++td)
      ktf[0][kb2][td] = *(const short8*)(KnT + (size_t)(wave*64 + td*16 + l15) * NK
                                         + (nbase + kb2*32 + quad*8));
  __syncthreads();   // drains chunk-0 staging

#pragma unroll 1
  for (int c = 0; c < CHUNKS; ++c) {
    const int cur = c & 1, nxt = cur ^ 1;
    const int n1 = nbase + (c + 1) * BN;   // next chunk base

    // ---- issue next chunk's staging + KnT prefetch FIRST (overlaps GEMM1)
    if (c + 1 < CHUNKS) {
#pragma unroll
      for (int i = 0; i < 8; ++i) {
        const int row = wave * 8 + i;
        load_lds16(Kn + (size_t)(n1 + row) * D + lane * 8, &K_lds[nxt][row * KROW]);
      }
#pragma unroll
      for (int kb2 = 0; kb2 < 2; ++kb2)
#pragma unroll
        for (int td = 0; td < 4; ++td)
          ktf[nxt][kb2][td] = *(const short8*)(KnT + (size_t)(wave*64 + td*16 + l15) * NK
                                               + (n1 + kb2*32 + quad*8));
    }

    // ---- GEMM1: S^T tiles (wave: 2 tn x 1 tb), A = K rows from LDS, B = qf
    floatx4 s0 = {}, s1 = {};
#pragma unroll
    for (int kb = 0; kb < 16; ++kb) {
      short8 a0 = *(const short8*)&K_lds[cur][(nh*32 +      l15) * KROW + kb*32 + quad*8];
      short8 a1 = *(const short8*)&K_lds[cur][(nh*32 + 16 + l15) * KROW + kb*32 + quad*8];
      s0 = __builtin_amdgcn_mfma_f32_16x16x32_bf16(a0, qf[kb], s0, 0, 0, 0);
      s1 = __builtin_amdgcn_mfma_f32_16x16x32_bf16(a1, qf[kb], s1, 0, 0, 0);
    }

    // ---- exp + pack to bf16, one 8B LDS write per tile
    {
      const int prow = (tb * 16 + l15) * PROW;
      uint2v w0, w1;
      w0.x = pack2(__expf(BETA * (s0[0] - 1.f)), __expf(BETA * (s0[1] - 1.f)));
      w0.y = pack2(__expf(BETA * (s0[2] - 1.f)), __expf(BETA * (s0[3] - 1.f)));
      w1.x = pack2(__expf(BETA * (s1[0] - 1.f)), __expf(BETA * (s1[1] - 1.f)));
      w1.y = pack2(__expf(BETA * (s1[2] - 1.f)), __expf(BETA * (s1[3] - 1.f)));
      *(uint2v*)&P_lds[cur][prow + (nh*2 + 0) * 16 + quad * 4] = w0;
      *(uint2v*)&P_lds[cur][prow + (nh*2 + 1) * 16 + quad * 4] = w1;
    }

    // ---- the ONLY barrier: P(c) visible; staging(c+1)/ktf(c+1) drained
    __syncthreads();

    // ---- GEMM2: O += P (LDS, A-op) * KnT (regs, B-op)
#pragma unroll
    for (int kb2 = 0; kb2 < 2; ++kb2) {
      short8 pf[4];
#pragma unroll
      for (int tr = 0; tr < 4; ++tr)
        pf[tr] = *(const short8*)&P_lds[cur][(tr*16 + l15) * PROW + kb2*32 + quad*8];
#pragma unroll
      for (int td = 0; td < 4; ++td)
#pragma unroll
        for (int tr = 0; tr < 4; ++tr)
          oacc[tr][td] = __builtin_amdgcn_mfma_f32_16x16x32_bf16(
              pf[tr], ktf[cur][kb2][td], oacc[tr][td], 0, 0, 0);
    }
  }

  // ---- epilogue: out += ALPHA * O  (out pre-initialized to Q by norm_q)
  const int colbase = wave * 64 + l15;
#pragma unroll
  for (int tr = 0; tr < 4; ++tr)
#pragma unroll
    for (int td = 0; td < 4; ++td)
#pragma unroll
      for (int r = 0; r < 4; ++r)
        atomicAdd(out + (size_t)(q0 + tr*16 + quad*4 + r) * D + colbase + td*16,
                  ALPHA * oacc[tr][td][r]);
}

extern "C" void kernel_launch(void* const* d_in, const int* in_sizes, int n_in,
                              void* d_out, int out_size, void* d_ws, size_t ws_size,
                              hipStream_t stream) {
  (void)in_sizes; (void)n_in; (void)out_size; (void)ws_size;
  const float* q = (const float*)d_in[0];
  const float* k = (const float*)d_in[1];
  float* out = (float*)d_out;
  unsigned short* Qn  = (unsigned short*)d_ws;          //  4 MB
  unsigned short* Kn  = Qn + (size_t)NB * D;            // 16 MB
  unsigned short* KnT = Kn + (size_t)NK * D;            // 16 MB  (total 36 MB)

  hipLaunchKernelGGL(norm_q_kernel, dim3(NB / 4),  dim3(256), 0, stream, q, out, Qn);
  hipLaunchKernelGGL(norm_k_kernel, dim3(NK / 64), dim3(256), 0, stream, k, Kn, KnT);
  hipLaunchKernelGGL(fused_kernel, dim3((NB / BQ) * NSPLIT), dim3(512), 0, stream,
                     Qn, Kn, KnT, out);
}

// Round 4
// 495.536 us; speedup vs baseline: 1.0403x; 1.0403x over previous
//
#include <hip/hip_runtime.h>
#include <cstdint>
#include <cstddef>

#define BETA 5.5f
#define ALPHA 0.5f

constexpr int D   = 512;     // feature dim
constexpr int NB  = 4096;    // queries
constexpr int NK  = 16384;   // keys
constexpr int BQ  = 64;      // query tile per block
constexpr int BN  = 64;      // key chunk
constexpr int NSPLIT = 4;
constexpr int NRANGE = NK / NSPLIT;   // 4096
constexpr int CHUNKS = NRANGE / BN;   // 64
constexpr int KROW = D + 8;           // padded LDS row (bf16 elems)
constexpr int PROW = BN + 8;          // padded P row: 72
constexpr int PART_BLK = BQ * D;      // 32768 floats per block-partial (128 KB)

typedef __attribute__((ext_vector_type(8))) short    short8;
typedef __attribute__((ext_vector_type(4))) float    floatx4;
typedef __attribute__((ext_vector_type(4))) uint32_t uint4v;
typedef __attribute__((ext_vector_type(2))) uint32_t uint2v;

__device__ inline uint32_t f2bf1(float f) {
  union { float f; uint32_t u; } v; v.f = f;
  return (v.u + 0x7FFFu + ((v.u >> 16) & 1u)) >> 16;   // RNE
}
__device__ inline uint32_t pack2(float a, float b) {
  return f2bf1(a) | (f2bf1(b) << 16);
}

__device__ inline void load_lds16(const void* g, void* l) {
  __builtin_amdgcn_global_load_lds(
      (const __attribute__((address_space(1))) uint32_t*)g,
      (__attribute__((address_space(3))) uint32_t*)l, 16, 0, 0);
}

// ---------------- normalize Q -> Qn (bf16) ----------------------------------
__global__ void norm_q_kernel(const float* __restrict__ q,
                              unsigned short* __restrict__ Qn) {
  const int wave = threadIdx.x >> 6, lane = threadIdx.x & 63;
  const int row = blockIdx.x * 4 + wave;
  const float4* qr = (const float4*)(q + (size_t)row * D);
  float4 a = qr[lane * 2];
  float4 b = qr[lane * 2 + 1];
  float ss = a.x*a.x + a.y*a.y + a.z*a.z + a.w*a.w
           + b.x*b.x + b.y*b.y + b.z*b.z + b.w*b.w;
#pragma unroll
  for (int m = 32; m >= 1; m >>= 1) ss += __shfl_xor(ss, m, 64);
  const float sc = 1.0f / fmaxf(sqrtf(ss), 1e-12f);
  uint4v w;
  w.x = pack2(a.x*sc, a.y*sc); w.y = pack2(a.z*sc, a.w*sc);
  w.z = pack2(b.x*sc, b.y*sc); w.w = pack2(b.z*sc, b.w*sc);
  *(uint4v*)(Qn + (size_t)row * D + lane * 8) = w;
}

// ------------- normalize K -> Kn (bf16) and KnT (bf16, transposed) ----------
__global__ void norm_k_kernel(const float* __restrict__ k,
                              unsigned short* __restrict__ Kn,
                              unsigned short* __restrict__ KnT) {
  __shared__ unsigned short tile[64 * KROW];
  const int wave = threadIdx.x >> 6, lane = threadIdx.x & 63;
  const int n0 = blockIdx.x * 64;
#pragma unroll 1
  for (int i = 0; i < 16; ++i) {
    const int rl = wave * 16 + i;
    const int n  = n0 + rl;
    const float4* kr = (const float4*)(k + (size_t)n * D);
    float4 a = kr[lane * 2], b = kr[lane * 2 + 1];
    float ss = a.x*a.x + a.y*a.y + a.z*a.z + a.w*a.w
             + b.x*b.x + b.y*b.y + b.z*b.z + b.w*b.w;
#pragma unroll
    for (int m = 32; m >= 1; m >>= 1) ss += __shfl_xor(ss, m, 64);
    const float sc = 1.0f / fmaxf(sqrtf(ss), 1e-12f);
    uint4v w;
    w.x = pack2(a.x*sc, a.y*sc); w.y = pack2(a.z*sc, a.w*sc);
    w.z = pack2(b.x*sc, b.y*sc); w.w = pack2(b.z*sc, b.w*sc);
    *(uint4v*)(Kn + (size_t)n * D + lane * 8) = w;
    *(uint4v*)&tile[rl * KROW + lane * 8]     = w;
  }
  __syncthreads();
  const int dsub = threadIdx.x >> 3;        // 0..31
  const int nl   = (threadIdx.x & 7) * 8;   // 0..56
#pragma unroll 1
  for (int iter = 0; iter < 16; ++iter) {
    const int d = iter * 32 + dsub;
    uint4v w;
    w.x = (uint32_t)tile[(nl+0)*KROW + d] | ((uint32_t)tile[(nl+1)*KROW + d] << 16);
    w.y = (uint32_t)tile[(nl+2)*KROW + d] | ((uint32_t)tile[(nl+3)*KROW + d] << 16);
    w.z = (uint32_t)tile[(nl+4)*KROW + d] | ((uint32_t)tile[(nl+5)*KROW + d] << 16);
    w.w = (uint32_t)tile[(nl+6)*KROW + d] | ((uint32_t)tile[(nl+7)*KROW + d] << 16);
    *(uint4v*)(KnT + (size_t)d * NK + n0 + nl) = w;
  }
}

// ---------------- fused: S = Qn Kn^T chunk, P = exp, Opart = P Kn -----------
// Pipelined (K_lds/P_lds/ktf double-buffered, ONE barrier per chunk).
// NO global atomics: each block streams its fp32 partial to ws (coalesced).
__global__ __launch_bounds__(512, 2) void fused_kernel(
    const unsigned short* __restrict__ Qn,
    const unsigned short* __restrict__ Kn,
    const unsigned short* __restrict__ KnT,
    float* __restrict__ part) {
  __shared__ unsigned short K_lds[2][BN * KROW];   // 2 x 66.5 KB
  __shared__ unsigned short P_lds[2][BQ * PROW];   // 2 x 9.2 KB   (total 148 KB)

  const int tid  = threadIdx.x;
  const int wave = tid >> 6, lane = tid & 63;
  const int l15  = lane & 15, quad = lane >> 4;
  const int nsplit = blockIdx.x & (NSPLIT - 1); // round-robin: 2 XCDs per nsplit
  const int qtile  = blockIdx.x >> 2;           // 0..63
  const int q0     = qtile * BQ;
  const int nbase  = nsplit * NRANGE;
  const int tb = wave & 3, nh = wave >> 2;

  // Q B-fragments in registers: wave's 16-col b-tile, all 512 d (64 VGPR)
  short8 qf[16];
  {
    const unsigned short* qrow = Qn + (size_t)(q0 + tb * 16 + l15) * D + quad * 8;
#pragma unroll
    for (int kb = 0; kb < 16; ++kb) qf[kb] = *(const short8*)(qrow + kb * 32);
  }

  floatx4 oacc[4][4] = {};   // wave's 64x64 O slice (cols wave*64..+63)
  short8 ktf[2][2][4];       // double-buffered KnT B-fragments

  // prologue: stage chunk 0 into buf0, prefetch its KnT frags
#pragma unroll
  for (int i = 0; i < 8; ++i) {
    const int row = wave * 8 + i;
    load_lds16(Kn + (size_t)(nbase + row) * D + lane * 8, &K_lds[0][row * KROW]);
  }
#pragma unroll
  for (int kb2 = 0; kb2 < 2; ++kb2)
#pragma unroll
    for (int td = 0; td < 4; ++td)
      ktf[0][kb2][td] = *(const short8*)(KnT + (size_t)(wave*64 + td*16 + l15) * NK
                                         + (nbase + kb2*32 + quad*8));
  __syncthreads();   // drains chunk-0 staging

#pragma unroll 1
  for (int c = 0; c < CHUNKS; ++c) {
    const int cur = c & 1, nxt = cur ^ 1;
    const int n1 = nbase + (c + 1) * BN;   // next chunk base

    // ---- issue next chunk's staging + KnT prefetch FIRST (overlaps GEMM1)
    if (c + 1 < CHUNKS) {
#pragma unroll
      for (int i = 0; i < 8; ++i) {
        const int row = wave * 8 + i;
        load_lds16(Kn + (size_t)(n1 + row) * D + lane * 8, &K_lds[nxt][row * KROW]);
      }
#pragma unroll
      for (int kb2 = 0; kb2 < 2; ++kb2)
#pragma unroll
        for (int td = 0; td < 4; ++td)
          ktf[nxt][kb2][td] = *(const short8*)(KnT + (size_t)(wave*64 + td*16 + l15) * NK
                                               + (n1 + kb2*32 + quad*8));
    }

    // ---- GEMM1: S^T tiles (wave: 2 tn x 1 tb), A = K rows from LDS, B = qf
    floatx4 s0 = {}, s1 = {};
#pragma unroll
    for (int kb = 0; kb < 16; ++kb) {
      short8 a0 = *(const short8*)&K_lds[cur][(nh*32 +      l15) * KROW + kb*32 + quad*8];
      short8 a1 = *(const short8*)&K_lds[cur][(nh*32 + 16 + l15) * KROW + kb*32 + quad*8];
      s0 = __builtin_amdgcn_mfma_f32_16x16x32_bf16(a0, qf[kb], s0, 0, 0, 0);
      s1 = __builtin_amdgcn_mfma_f32_16x16x32_bf16(a1, qf[kb], s1, 0, 0, 0);
    }

    // ---- exp + pack to bf16, one 8B LDS write per tile
    {
      const int prow = (tb * 16 + l15) * PROW;
      uint2v w0, w1;
      w0.x = pack2(__expf(BETA * (s0[0] - 1.f)), __expf(BETA * (s0[1] - 1.f)));
      w0.y = pack2(__expf(BETA * (s0[2] - 1.f)), __expf(BETA * (s0[3] - 1.f)));
      w1.x = pack2(__expf(BETA * (s1[0] - 1.f)), __expf(BETA * (s1[1] - 1.f)));
      w1.y = pack2(__expf(BETA * (s1[2] - 1.f)), __expf(BETA * (s1[3] - 1.f)));
      *(uint2v*)&P_lds[cur][prow + (nh*2 + 0) * 16 + quad * 4] = w0;
      *(uint2v*)&P_lds[cur][prow + (nh*2 + 1) * 16 + quad * 4] = w1;
    }

    // ---- the ONLY barrier: P(c) visible; staging(c+1)/ktf(c+1) drained
    __syncthreads();

    // ---- GEMM2: O += P (LDS, A-op) * KnT (regs, B-op)
#pragma unroll
    for (int kb2 = 0; kb2 < 2; ++kb2) {
      short8 pf[4];
#pragma unroll
      for (int tr = 0; tr < 4; ++tr)
        pf[tr] = *(const short8*)&P_lds[cur][(tr*16 + l15) * PROW + kb2*32 + quad*8];
#pragma unroll
      for (int td = 0; td < 4; ++td)
#pragma unroll
        for (int tr = 0; tr < 4; ++tr)
          oacc[tr][td] = __builtin_amdgcn_mfma_f32_16x16x32_bf16(
              pf[tr], ktf[cur][kb2][td], oacc[tr][td], 0, 0, 0);
    }
  }

  // ---- epilogue: stream fp32 partial to ws, fully coalesced (1KB/instr).
  // Layout (scrambled but consistent; reduce kernel mirrors it):
  //   part[(qtile*NSPLIT+ns)*32768 + wave*4096 + (tr*4+td)*256 + lane*4 + r]
  float* pb = part + (size_t)blockIdx.x * PART_BLK + wave * 4096;
#pragma unroll
  for (int tr = 0; tr < 4; ++tr)
#pragma unroll
    for (int td = 0; td < 4; ++td) {
      float4 v = { oacc[tr][td][0], oacc[tr][td][1], oacc[tr][td][2], oacc[tr][td][3] };
      *(float4*)(pb + (tr * 4 + td) * 256 + lane * 4) = v;
    }
}

// ---------------- reduce: out = Q + ALPHA * sum_ns partial ------------------
__global__ void reduce_kernel(const float* __restrict__ q,
                              const float* __restrict__ part,
                              float* __restrict__ out) {
  const int qtile = blockIdx.x;
  const int tid = threadIdx.x;
  const int wave = tid >> 6, lane = tid & 63;
  const int l15 = lane & 15, quad = lane >> 4;
  const int q0 = qtile * BQ;
  const float* pb = part + (size_t)qtile * NSPLIT * PART_BLK + wave * 4096;
#pragma unroll
  for (int tr = 0; tr < 4; ++tr)
#pragma unroll
    for (int td = 0; td < 4; ++td) {
      const int off = (tr * 4 + td) * 256 + lane * 4;
      float4 s = *(const float4*)(pb + off);
      float4 s1 = *(const float4*)(pb + PART_BLK + off);
      float4 s2 = *(const float4*)(pb + 2 * PART_BLK + off);
      float4 s3 = *(const float4*)(pb + 3 * PART_BLK + off);
      s.x += s1.x + s2.x + s3.x;  s.y += s1.y + s2.y + s3.y;
      s.z += s1.z + s2.z + s3.z;  s.w += s1.w + s2.w + s3.w;
      const int col = wave * 64 + td * 16 + l15;
      const int row0 = q0 + tr * 16 + quad * 4;
      out[(size_t)(row0 + 0) * D + col] = q[(size_t)(row0 + 0) * D + col] + ALPHA * s.x;
      out[(size_t)(row0 + 1) * D + col] = q[(size_t)(row0 + 1) * D + col] + ALPHA * s.y;
      out[(size_t)(row0 + 2) * D + col] = q[(size_t)(row0 + 2) * D + col] + ALPHA * s.z;
      out[(size_t)(row0 + 3) * D + col] = q[(size_t)(row0 + 3) * D + col] + ALPHA * s.w;
    }
}

extern "C" void kernel_launch(void* const* d_in, const int* in_sizes, int n_in,
                              void* d_out, int out_size, void* d_ws, size_t ws_size,
                              hipStream_t stream) {
  (void)in_sizes; (void)n_in; (void)out_size; (void)ws_size;
  const float* q = (const float*)d_in[0];
  const float* k = (const float*)d_in[1];
  float* out = (float*)d_out;
  unsigned short* Qn  = (unsigned short*)d_ws;          //  4 MB
  unsigned short* Kn  = Qn + (size_t)NB * D;            // 16 MB
  unsigned short* KnT = Kn + (size_t)NK * D;            // 16 MB
  float* part = (float*)(KnT + (size_t)D * NK);         // 32 MB  (total 68 MB)

  hipLaunchKernelGGL(norm_q_kernel, dim3(NB / 4),  dim3(256), 0, stream, q, Qn);
  hipLaunchKernelGGL(norm_k_kernel, dim3(NK / 64), dim3(256), 0, stream, k, Kn, KnT);
  hipLaunchKernelGGL(fused_kernel, dim3((NB / BQ) * NSPLIT), dim3(512), 0, stream,
                     Qn, Kn, KnT, part);
  hipLaunchKernelGGL(reduce_kernel, dim3(NB / BQ), dim3(512), 0, stream, q, part, out);
}

// Round 5
// 343.569 us; speedup vs baseline: 1.5005x; 1.4423x over previous
//
#include <hip/hip_runtime.h>
#include <cstdint>
#include <cstddef>

#define BETA 5.5f
#define ALPHA 0.5f

constexpr int D   = 512;     // feature dim
constexpr int NB  = 4096;    // queries
constexpr int NK  = 16384;   // keys
constexpr int BQ  = 64;      // query tile per block
constexpr int BN  = 64;      // key chunk
constexpr int NSPLIT = 4;
constexpr int NRANGE = NK / NSPLIT;   // 4096
constexpr int CHUNKS = NRANGE / BN;   // 64
constexpr int KROW = D + 8;           // padded LDS row (bf16 elems)
constexpr int PROW = BN + 8;          // padded P row: 72
constexpr int PART_BLK = BQ * D;      // 32768 floats per block-partial (128 KB)

typedef __attribute__((ext_vector_type(8))) short    short8;
typedef __attribute__((ext_vector_type(4))) float    floatx4;
typedef __attribute__((ext_vector_type(4))) uint32_t uint4v;
typedef __attribute__((ext_vector_type(2))) uint32_t uint2v;

__device__ inline uint32_t f2bf1(float f) {
  union { float f; uint32_t u; } v; v.f = f;
  return (v.u + 0x7FFFu + ((v.u >> 16) & 1u)) >> 16;   // RNE
}
__device__ inline uint32_t pack2(float a, float b) {
  return f2bf1(a) | (f2bf1(b) << 16);
}

__device__ inline void load_lds16(const void* g, void* l) {
  __builtin_amdgcn_global_load_lds(
      (const __attribute__((address_space(1))) uint32_t*)g,
      (__attribute__((address_space(3))) uint32_t*)l, 16, 0, 0);
}

// ---------------- normalize Q -> Qn (bf16) ----------------------------------
__global__ void norm_q_kernel(const float* __restrict__ q,
                              unsigned short* __restrict__ Qn) {
  const int wave = threadIdx.x >> 6, lane = threadIdx.x & 63;
  const int row = blockIdx.x * 4 + wave;
  const float4* qr = (const float4*)(q + (size_t)row * D);
  float4 a = qr[lane * 2];
  float4 b = qr[lane * 2 + 1];
  float ss = a.x*a.x + a.y*a.y + a.z*a.z + a.w*a.w
           + b.x*b.x + b.y*b.y + b.z*b.z + b.w*b.w;
#pragma unroll
  for (int m = 32; m >= 1; m >>= 1) ss += __shfl_xor(ss, m, 64);
  const float sc = 1.0f / fmaxf(sqrtf(ss), 1e-12f);
  uint4v w;
  w.x = pack2(a.x*sc, a.y*sc); w.y = pack2(a.z*sc, a.w*sc);
  w.z = pack2(b.x*sc, b.y*sc); w.w = pack2(b.z*sc, b.w*sc);
  *(uint4v*)(Qn + (size_t)row * D + lane * 8) = w;
}

// ------------- normalize K -> Kn (bf16) and KnT (bf16, transposed) ----------
__global__ void norm_k_kernel(const float* __restrict__ k,
                              unsigned short* __restrict__ Kn,
                              unsigned short* __restrict__ KnT) {
  __shared__ unsigned short tile[64 * KROW];
  const int wave = threadIdx.x >> 6, lane = threadIdx.x & 63;
  const int n0 = blockIdx.x * 64;
#pragma unroll 1
  for (int i = 0; i < 16; ++i) {
    const int rl = wave * 16 + i;
    const int n  = n0 + rl;
    const float4* kr = (const float4*)(k + (size_t)n * D);
    float4 a = kr[lane * 2], b = kr[lane * 2 + 1];
    float ss = a.x*a.x + a.y*a.y + a.z*a.z + a.w*a.w
             + b.x*b.x + b.y*b.y + b.z*b.z + b.w*b.w;
#pragma unroll
    for (int m = 32; m >= 1; m >>= 1) ss += __shfl_xor(ss, m, 64);
    const float sc = 1.0f / fmaxf(sqrtf(ss), 1e-12f);
    uint4v w;
    w.x = pack2(a.x*sc, a.y*sc); w.y = pack2(a.z*sc, a.w*sc);
    w.z = pack2(b.x*sc, b.y*sc); w.w = pack2(b.z*sc, b.w*sc);
    *(uint4v*)(Kn + (size_t)n * D + lane * 8) = w;
    *(uint4v*)&tile[rl * KROW + lane * 8]     = w;
  }
  __syncthreads();
  const int dsub = threadIdx.x >> 3;        // 0..31
  const int nl   = (threadIdx.x & 7) * 8;   // 0..56
#pragma unroll 1
  for (int iter = 0; iter < 16; ++iter) {
    const int d = iter * 32 + dsub;
    uint4v w;
    w.x = (uint32_t)tile[(nl+0)*KROW + d] | ((uint32_t)tile[(nl+1)*KROW + d] << 16);
    w.y = (uint32_t)tile[(nl+2)*KROW + d] | ((uint32_t)tile[(nl+3)*KROW + d] << 16);
    w.z = (uint32_t)tile[(nl+4)*KROW + d] | ((uint32_t)tile[(nl+5)*KROW + d] << 16);
    w.w = (uint32_t)tile[(nl+6)*KROW + d] | ((uint32_t)tile[(nl+7)*KROW + d] << 16);
    *(uint4v*)(KnT + (size_t)d * NK + n0 + nl) = w;
  }
}

// ---------------- fused: S = Qn Kn^T chunk, P = exp, Opart = P Kn -----------
// Pipelined: K_lds/P_lds double-buffered, ONE barrier per chunk.
// ktf is SINGLE-buffered, prefetched right after GEMM2 consumes it (the
// round-2 ktf double-buffer pushed past the 2-wave/SIMD register budget and
// spilled 32 regs/iter to scratch = 1.07 GB of write traffic).
__global__ __launch_bounds__(512, 2) void fused_kernel(
    const unsigned short* __restrict__ Qn,
    const unsigned short* __restrict__ Kn,
    const unsigned short* __restrict__ KnT,
    float* __restrict__ part) {
  __shared__ unsigned short K_lds[2][BN * KROW];   // 2 x 66.5 KB
  __shared__ unsigned short P_lds[2][BQ * PROW];   // 2 x 9.2 KB   (total 151 KB)

  const int tid  = threadIdx.x;
  const int wave = tid >> 6, lane = tid & 63;
  const int l15  = lane & 15, quad = lane >> 4;
  const int nsplit = blockIdx.x & (NSPLIT - 1);
  const int qtile  = blockIdx.x >> 2;           // 0..63
  const int q0     = qtile * BQ;
  const int nbase  = nsplit * NRANGE;
  const int tb = wave & 3, nh = wave >> 2;

  // Q B-fragments in registers: wave's 16-col b-tile, all 512 d (64 VGPR)
  short8 qf[16];
  {
    const unsigned short* qrow = Qn + (size_t)(q0 + tb * 16 + l15) * D + quad * 8;
#pragma unroll
    for (int kb = 0; kb < 16; ++kb) qf[kb] = *(const short8*)(qrow + kb * 32);
  }

  floatx4 oacc[4][4] = {};   // wave's 64x64 O slice (cols wave*64..+63)
  short8 ktf[2][4];          // SINGLE-buffered KnT B-fragments (32 VGPR)

  // prologue: stage chunk 0 into buf0, load its KnT frags
#pragma unroll
  for (int i = 0; i < 8; ++i) {
    const int row = wave * 8 + i;
    load_lds16(Kn + (size_t)(nbase + row) * D + lane * 8, &K_lds[0][row * KROW]);
  }
#pragma unroll
  for (int kb2 = 0; kb2 < 2; ++kb2)
#pragma unroll
    for (int td = 0; td < 4; ++td)
      ktf[kb2][td] = *(const short8*)(KnT + (size_t)(wave*64 + td*16 + l15) * NK
                                      + (nbase + kb2*32 + quad*8));
  __syncthreads();   // drains chunk-0 staging

#pragma unroll 1
  for (int c = 0; c < CHUNKS; ++c) {
    const int cur = c & 1, nxt = cur ^ 1;
    const int n1 = nbase + (c + 1) * BN;   // next chunk base

    // ---- issue next chunk's K staging FIRST (overlaps GEMM1; drained at barrier)
    if (c + 1 < CHUNKS) {
#pragma unroll
      for (int i = 0; i < 8; ++i) {
        const int row = wave * 8 + i;
        load_lds16(Kn + (size_t)(n1 + row) * D + lane * 8, &K_lds[nxt][row * KROW]);
      }
    }

    // ---- GEMM1: S^T tiles (wave: 2 tn x 1 tb), A = K rows from LDS, B = qf
    floatx4 s0 = {}, s1 = {};
#pragma unroll
    for (int kb = 0; kb < 16; ++kb) {
      short8 a0 = *(const short8*)&K_lds[cur][(nh*32 +      l15) * KROW + kb*32 + quad*8];
      short8 a1 = *(const short8*)&K_lds[cur][(nh*32 + 16 + l15) * KROW + kb*32 + quad*8];
      s0 = __builtin_amdgcn_mfma_f32_16x16x32_bf16(a0, qf[kb], s0, 0, 0, 0);
      s1 = __builtin_amdgcn_mfma_f32_16x16x32_bf16(a1, qf[kb], s1, 0, 0, 0);
    }

    // ---- exp + pack to bf16, one 8B LDS write per tile
    {
      const int prow = (tb * 16 + l15) * PROW;
      uint2v w0, w1;
      w0.x = pack2(__expf(BETA * (s0[0] - 1.f)), __expf(BETA * (s0[1] - 1.f)));
      w0.y = pack2(__expf(BETA * (s0[2] - 1.f)), __expf(BETA * (s0[3] - 1.f)));
      w1.x = pack2(__expf(BETA * (s1[0] - 1.f)), __expf(BETA * (s1[1] - 1.f)));
      w1.y = pack2(__expf(BETA * (s1[2] - 1.f)), __expf(BETA * (s1[3] - 1.f)));
      *(uint2v*)&P_lds[cur][prow + (nh*2 + 0) * 16 + quad * 4] = w0;
      *(uint2v*)&P_lds[cur][prow + (nh*2 + 1) * 16 + quad * 4] = w1;
    }

    // ---- the ONLY barrier: P(c) visible; staging(c+1) + ktf(c) drained
    __syncthreads();

    // ---- GEMM2: O += P (LDS, A-op) * KnT (regs, B-op)
#pragma unroll
    for (int kb2 = 0; kb2 < 2; ++kb2) {
      short8 pf[4];
#pragma unroll
      for (int tr = 0; tr < 4; ++tr)
        pf[tr] = *(const short8*)&P_lds[cur][(tr*16 + l15) * PROW + kb2*32 + quad*8];
#pragma unroll
      for (int td = 0; td < 4; ++td)
#pragma unroll
        for (int tr = 0; tr < 4; ++tr)
          oacc[tr][td] = __builtin_amdgcn_mfma_f32_16x16x32_bf16(
              pf[tr], ktf[kb2][td], oacc[tr][td], 0, 0, 0);
    }

    // ---- prefetch next chunk's KnT frags into the SAME regs (after use);
    //      arrival covered by barrier(c+1)'s vmcnt drain, ~GEMM1 away
    if (c + 1 < CHUNKS) {
#pragma unroll
      for (int kb2 = 0; kb2 < 2; ++kb2)
#pragma unroll
        for (int td = 0; td < 4; ++td)
          ktf[kb2][td] = *(const short8*)(KnT + (size_t)(wave*64 + td*16 + l15) * NK
                                          + (n1 + kb2*32 + quad*8));
    }
  }

  // ---- epilogue: stream fp32 partial to ws, fully coalesced (1KB/instr).
  float* pb = part + (size_t)blockIdx.x * PART_BLK + wave * 4096;
#pragma unroll
  for (int tr = 0; tr < 4; ++tr)
#pragma unroll
    for (int td = 0; td < 4; ++td) {
      float4 v = { oacc[tr][td][0], oacc[tr][td][1], oacc[tr][td][2], oacc[tr][td][3] };
      *(float4*)(pb + (tr * 4 + td) * 256 + lane * 4) = v;
    }
}

// ---------------- reduce: out = Q + ALPHA * sum_ns partial ------------------
__global__ void reduce_kernel(const float* __restrict__ q,
                              const float* __restrict__ part,
                              float* __restrict__ out) {
  const int qtile = blockIdx.x;
  const int tid = threadIdx.x;
  const int wave = tid >> 6, lane = tid & 63;
  const int l15 = lane & 15, quad = lane >> 4;
  const int q0 = qtile * BQ;
  const float* pb = part + (size_t)qtile * NSPLIT * PART_BLK + wave * 4096;
#pragma unroll
  for (int tr = 0; tr < 4; ++tr)
#pragma unroll
    for (int td = 0; td < 4; ++td) {
      const int off = (tr * 4 + td) * 256 + lane * 4;
      float4 s = *(const float4*)(pb + off);
      float4 s1 = *(const float4*)(pb + PART_BLK + off);
      float4 s2 = *(const float4*)(pb + 2 * PART_BLK + off);
      float4 s3 = *(const float4*)(pb + 3 * PART_BLK + off);
      s.x += s1.x + s2.x + s3.x;  s.y += s1.y + s2.y + s3.y;
      s.z += s1.z + s2.z + s3.z;  s.w += s1.w + s2.w + s3.w;
      const int col = wave * 64 + td * 16 + l15;
      const int row0 = q0 + tr * 16 + quad * 4;
      out[(size_t)(row0 + 0) * D + col] = q[(size_t)(row0 + 0) * D + col] + ALPHA * s.x;
      out[(size_t)(row0 + 1) * D + col] = q[(size_t)(row0 + 1) * D + col] + ALPHA * s.y;
      out[(size_t)(row0 + 2) * D + col] = q[(size_t)(row0 + 2) * D + col] + ALPHA * s.z;
      out[(size_t)(row0 + 3) * D + col] = q[(size_t)(row0 + 3) * D + col] + ALPHA * s.w;
    }
}

extern "C" void kernel_launch(void* const* d_in, const int* in_sizes, int n_in,
                              void* d_out, int out_size, void* d_ws, size_t ws_size,
                              hipStream_t stream) {
  (void)in_sizes; (void)n_in; (void)out_size; (void)ws_size;
  const float* q = (const float*)d_in[0];
  const float* k = (const float*)d_in[1];
  float* out = (float*)d_out;
  unsigned short* Qn  = (unsigned short*)d_ws;          //  4 MB
  unsigned short* Kn  = Qn + (size_t)NB * D;            // 16 MB
  unsigned short* KnT = Kn + (size_t)NK * D;            // 16 MB
  float* part = (float*)(KnT + (size_t)D * NK);         // 32 MB  (total 68 MB)

  hipLaunchKernelGGL(norm_q_kernel, dim3(NB / 4),  dim3(256), 0, stream, q, Qn);
  hipLaunchKernelGGL(norm_k_kernel, dim3(NK / 64), dim3(256), 0, stream, k, Kn, KnT);
  hipLaunchKernelGGL(fused_kernel, dim3((NB / BQ) * NSPLIT), dim3(512), 0, stream,
                     Qn, Kn, KnT, part);
  hipLaunchKernelGGL(reduce_kernel, dim3(NB / BQ), dim3(512), 0, stream, q, part, out);
}